// Round 1
// baseline (766.762 us; speedup 1.0000x reference)
//
#include <hip/hip_runtime.h>
#include <hip/hip_bf16.h>

// Problem constants (from reference)
#define N_NODES 50000
#define N_EDGES 500000
#define N_GRAPH 128
#define F_IN    16
#define LATENT  128
#define STEPS   3
#define LN_EPS  1e-6f
#define OUT_G   10

// ---------------- degree kernels ----------------
__global__ __launch_bounds__(256) void deg_init(float* deg_s, float* deg_r, int N) {
    int i = blockIdx.x * 256 + threadIdx.x;
    if (i < N) { deg_s[i] = 1.0f; deg_r[i] = 1.0f; }  // self edge
}

__global__ __launch_bounds__(256) void deg_count(const int* __restrict__ s, const int* __restrict__ r,
                                                 float* deg_s, float* deg_r, int E) {
    int e = blockIdx.x * 256 + threadIdx.x;
    if (e < E) {
        atomicAdd(&deg_s[s[e]], 1.0f);
        atomicAdd(&deg_r[r[e]], 1.0f);
    }
}

// exclusive scan of (deg_r - 1) over N elements, single block of 1024 threads.
// Also zeroes the cursor array. row_start[N] = total edge count.
__global__ __launch_bounds__(1024) void scan50k(const float* __restrict__ deg_r,
                                                int* __restrict__ row_start,
                                                int* __restrict__ cursor, int N) {
    __shared__ int wsum[16];
    __shared__ int carry;
    int tid = threadIdx.x, lane = tid & 63, wid = tid >> 6;
    if (tid == 0) carry = 0;
    __syncthreads();
    for (int base = 0; base < N; base += 1024) {
        int i = base + tid;
        int vv = (i < N) ? ((int)deg_r[i] - 1) : 0;
        int x = vv;
        #pragma unroll
        for (int off = 1; off < 64; off <<= 1) {
            int y = __shfl_up(x, off);
            if (lane >= off) x += y;
        }
        if (lane == 63) wsum[wid] = x;
        __syncthreads();
        if (tid == 0) {
            int acc = carry;
            #pragma unroll
            for (int w = 0; w < 16; ++w) { int t = wsum[w]; wsum[w] = acc; acc += t; }
            carry = acc;
        }
        __syncthreads();
        if (i < N) {
            row_start[i] = wsum[wid] + (x - vv);
            cursor[i] = 0;
        }
        __syncthreads();
    }
    if (tid == 0) row_start[N] = carry;
}

__global__ __launch_bounds__(256) void deg_fin(float* deg_s, float* deg_r, int N) {
    int i = blockIdx.x * 256 + threadIdx.x;
    if (i < N) {
        deg_s[i] = 1.0f / sqrtf(fmaxf(deg_s[i], 1.0f));  // becomes inv_sqrt_deg_s
        deg_r[i] = 1.0f / sqrtf(fmaxf(deg_r[i], 1.0f));  // becomes inv_sqrt_deg_r
    }
}

__global__ __launch_bounds__(256) void csr_fill(const int* __restrict__ s, const int* __restrict__ r,
                                                const int* __restrict__ row_start, int* cursor,
                                                int* __restrict__ csr_src, int E) {
    int e = blockIdx.x * 256 + threadIdx.x;
    if (e < E) {
        int rr = r[e];
        int slot = atomicAdd(&cursor[rr], 1);
        csr_src[row_start[rr] + slot] = s[e];
    }
}

// ---------------- embed: h = x @ W_embed + b_embed ----------------
__global__ __launch_bounds__(256) void embed_kernel(const float* __restrict__ x,
                                                    const float* __restrict__ W,
                                                    const float* __restrict__ b,
                                                    float* __restrict__ h, int N) {
    int idx = blockIdx.x * 256 + threadIdx.x;
    if (idx >= N * LATENT) return;
    int n = idx >> 7, j = idx & 127;
    float sacc = b[j];
    #pragma unroll
    for (int k = 0; k < F_IN; ++k) sacc = fmaf(x[n * F_IN + k], W[k * LATENT + j], sacc);
    h[idx] = sacc;
}

// ---------------- fused 2-layer MLP + inv_sqrt_deg_s scale ----------------
// block = 256 threads, 16 nodes per block; thread (j = tid&127, half = tid>>7)
// computes output column j for 8 nodes.
__global__ __launch_bounds__(256) void mlp_kernel(const float* __restrict__ h,
                                                  const float* __restrict__ W0, const float* __restrict__ b0,
                                                  const float* __restrict__ W1, const float* __restrict__ b1,
                                                  const float* __restrict__ inv_s,
                                                  float* __restrict__ v) {
    __shared__ __align__(16) float hs[16 * 128];
    __shared__ __align__(16) float us[16 * 128];
    int tid = threadIdx.x;
    int base = blockIdx.x * 16;

    for (int i = tid; i < 16 * 128; i += 256) hs[i] = h[base * 128 + i];
    __syncthreads();

    int j = tid & 127;
    int r0 = (tid >> 7) * 8;
    float acc[8];

    // layer 1
    {
        float bb = b0[j];
        #pragma unroll
        for (int q = 0; q < 8; ++q) acc[q] = bb;
        for (int k = 0; k < 128; k += 4) {
            float w0 = W0[(k + 0) * 128 + j];
            float w1 = W0[(k + 1) * 128 + j];
            float w2 = W0[(k + 2) * 128 + j];
            float w3 = W0[(k + 3) * 128 + j];
            #pragma unroll
            for (int q = 0; q < 8; ++q) {
                float4 hv = *reinterpret_cast<const float4*>(&hs[(r0 + q) * 128 + k]);
                acc[q] = fmaf(hv.x, w0, acc[q]);
                acc[q] = fmaf(hv.y, w1, acc[q]);
                acc[q] = fmaf(hv.z, w2, acc[q]);
                acc[q] = fmaf(hv.w, w3, acc[q]);
            }
        }
        #pragma unroll
        for (int q = 0; q < 8; ++q) us[(r0 + q) * 128 + j] = tanhf(acc[q]);
    }
    __syncthreads();

    // layer 2 + scale
    {
        float bb = b1[j];
        #pragma unroll
        for (int q = 0; q < 8; ++q) acc[q] = bb;
        for (int k = 0; k < 128; k += 4) {
            float w0 = W1[(k + 0) * 128 + j];
            float w1 = W1[(k + 1) * 128 + j];
            float w2 = W1[(k + 2) * 128 + j];
            float w3 = W1[(k + 3) * 128 + j];
            #pragma unroll
            for (int q = 0; q < 8; ++q) {
                float4 hv = *reinterpret_cast<const float4*>(&us[(r0 + q) * 128 + k]);
                acc[q] = fmaf(hv.x, w0, acc[q]);
                acc[q] = fmaf(hv.y, w1, acc[q]);
                acc[q] = fmaf(hv.z, w2, acc[q]);
                acc[q] = fmaf(hv.w, w3, acc[q]);
            }
        }
        #pragma unroll
        for (int q = 0; q < 8; ++q) {
            int n = base + r0 + q;
            v[n * 128 + j] = tanhf(acc[q]) * inv_s[n];
        }
    }
}

// ---------------- fused gather-aggregate + inv_r + skip + LayerNorm ----------------
// one 64-lane wave per node, 2 dims per lane; block = 4 waves = 4 nodes
__global__ __launch_bounds__(256) void agg_ln_kernel(const float* __restrict__ v,
                                                     const int* __restrict__ row_start,
                                                     const int* __restrict__ csr_src,
                                                     const float* __restrict__ inv_r,
                                                     const float* __restrict__ ln_scale,
                                                     const float* __restrict__ ln_bias,
                                                     float* __restrict__ h) {
    int lane = threadIdx.x & 63;
    int wave = threadIdx.x >> 6;
    int n = blockIdx.x * 4 + wave;
    int c0 = lane * 2;

    float2 acc = *reinterpret_cast<const float2*>(&v[n * 128 + c0]);  // self edge
    int lo = row_start[n], hi = row_start[n + 1];
    for (int p = lo; p < hi; ++p) {
        int src = csr_src[p];
        float2 t = *reinterpret_cast<const float2*>(&v[src * 128 + c0]);
        acc.x += t.x; acc.y += t.y;
    }
    float ir = inv_r[n];
    float2 hr = *reinterpret_cast<const float2*>(&h[n * 128 + c0]);
    float vx = fmaf(acc.x, ir, hr.x);
    float vy = fmaf(acc.y, ir, hr.y);

    float sred = vx + vy;
    #pragma unroll
    for (int off = 32; off; off >>= 1) sred += __shfl_xor(sred, off);
    float mu = sred * (1.0f / 128.0f);
    float dx = vx - mu, dy = vy - mu;
    float q = dx * dx + dy * dy;
    #pragma unroll
    for (int off = 32; off; off >>= 1) q += __shfl_xor(q, off);
    float rs = 1.0f / sqrtf(q * (1.0f / 128.0f) + LN_EPS);

    float2 outv;
    outv.x = fmaf(dx * rs, ln_scale[c0],     ln_bias[c0]);
    outv.y = fmaf(dy * rs, ln_scale[c0 + 1], ln_bias[c0 + 1]);
    *reinterpret_cast<float2*>(&h[n * 128 + c0]) = outv;
}

// ---------------- segment-mean pool (graph_ids sorted) ----------------
__global__ __launch_bounds__(128) void pool_kernel(const float* __restrict__ h,
                                                   const int* __restrict__ gids,
                                                   float* __restrict__ pooled, int N) {
    int g = blockIdx.x;
    int j = threadIdx.x;
    int lo = 0, hi = N;
    while (lo < hi) { int m = (lo + hi) >> 1; if (gids[m] < g) lo = m + 1; else hi = m; }
    int start = lo;
    lo = 0; hi = N;
    while (lo < hi) { int m = (lo + hi) >> 1; if (gids[m] < g + 1) lo = m + 1; else hi = m; }
    int end = lo;
    float sacc = 0.0f;
    for (int n = start; n < end; ++n) sacc += h[n * 128 + j];
    int cnt = end - start;
    pooled[g * 128 + j] = sacc / (float)max(cnt, 1);
}

// ---------------- decode: out = pooled @ W_dec + b_dec ----------------
__global__ __launch_bounds__(128) void decode_kernel(const float* __restrict__ pooled,
                                                     const float* __restrict__ W_dec,
                                                     const float* __restrict__ b_dec,
                                                     float* __restrict__ out) {
    __shared__ float pl[128];
    int g = blockIdx.x;
    pl[threadIdx.x] = pooled[g * 128 + threadIdx.x];
    __syncthreads();
    if (threadIdx.x < OUT_G) {
        int o = threadIdx.x;
        float sacc = b_dec[o];
        for (int jj = 0; jj < 128; ++jj) sacc = fmaf(pl[jj], W_dec[jj * OUT_G + o], sacc);
        out[g * OUT_G + o] = sacc;
    }
}

extern "C" void kernel_launch(void* const* d_in, const int* in_sizes, int n_in,
                              void* d_out, int out_size, void* d_ws, size_t ws_size,
                              hipStream_t stream) {
    const float* x        = (const float*)d_in[0];
    const int*   senders  = (const int*)d_in[1];
    const int*   receivers= (const int*)d_in[2];
    const int*   gids     = (const int*)d_in[3];
    const float* W_embed  = (const float*)d_in[4];
    const float* b_embed  = (const float*)d_in[5];
    const float* W_mlp    = (const float*)d_in[6];
    const float* b_mlp    = (const float*)d_in[7];
    const float* ln_scale = (const float*)d_in[8];
    const float* ln_bias  = (const float*)d_in[9];
    const float* W_dec    = (const float*)d_in[10];
    const float* b_dec    = (const float*)d_in[11];
    float* out = (float*)d_out;

    const int N = N_NODES, E = N_EDGES;
    char* ws = (char*)d_ws;
    size_t off = 0;
    auto alloc = [&](size_t bytes) { size_t o = off; off = (off + bytes + 255) & ~(size_t)255; return o; };
    float* h        = (float*)(ws + alloc((size_t)N * 128 * 4));
    float* v        = (float*)(ws + alloc((size_t)N * 128 * 4));
    float* deg_s    = (float*)(ws + alloc((size_t)N * 4));      // becomes inv_sqrt_deg_s
    float* deg_r    = (float*)(ws + alloc((size_t)N * 4));      // becomes inv_sqrt_deg_r
    int*   row_start= (int*)  (ws + alloc((size_t)(N + 1) * 4));
    int*   cursor   = (int*)  (ws + alloc((size_t)N * 4));
    int*   csr_src  = (int*)  (ws + alloc((size_t)E * 4));
    float* pooled   = (float*)(ws + alloc((size_t)N_GRAPH * 128 * 4));

    deg_init <<<(N + 255) / 256, 256, 0, stream>>>(deg_s, deg_r, N);
    deg_count<<<(E + 255) / 256, 256, 0, stream>>>(senders, receivers, deg_s, deg_r, E);
    scan50k  <<<1, 1024, 0, stream>>>(deg_r, row_start, cursor, N);     // reads raw deg_r
    deg_fin  <<<(N + 255) / 256, 256, 0, stream>>>(deg_s, deg_r, N);    // in-place -> inv
    csr_fill <<<(E + 255) / 256, 256, 0, stream>>>(senders, receivers, row_start, cursor, csr_src, E);

    embed_kernel<<<(N * 128) / 256, 256, 0, stream>>>(x, W_embed, b_embed, h, N);

    for (int t = 0; t < STEPS; ++t) {
        const float* W0 = W_mlp + (size_t)(t * 2 + 0) * 128 * 128;
        const float* b0 = b_mlp + (size_t)(t * 2 + 0) * 128;
        const float* W1 = W_mlp + (size_t)(t * 2 + 1) * 128 * 128;
        const float* b1 = b_mlp + (size_t)(t * 2 + 1) * 128;
        mlp_kernel  <<<N / 16, 256, 0, stream>>>(h, W0, b0, W1, b1, deg_s, v);
        agg_ln_kernel<<<N / 4, 256, 0, stream>>>(v, row_start, csr_src, deg_r,
                                                 ln_scale + t * 128, ln_bias + t * 128, h);
    }

    pool_kernel  <<<N_GRAPH, 128, 0, stream>>>(h, gids, pooled, N);
    decode_kernel<<<N_GRAPH, 128, 0, stream>>>(pooled, W_dec, b_dec, out);
}

// Round 2
// 685.930 us; speedup vs baseline: 1.1178x; 1.1178x over previous
//
#include <hip/hip_runtime.h>
#include <hip/hip_bf16.h>

// Problem constants (from reference)
#define N_NODES 50000
#define N_EDGES 500000
#define N_GRAPH 128
#define F_IN    16
#define LATENT  128
#define STEPS   3
#define LN_EPS  1e-6f
#define OUT_G   10

// ---------------- degree kernels ----------------
__global__ __launch_bounds__(256) void deg_init(float* deg_s, float* deg_r, int N) {
    int i = blockIdx.x * 256 + threadIdx.x;
    if (i < N) { deg_s[i] = 1.0f; deg_r[i] = 1.0f; }  // self edge
}

__global__ __launch_bounds__(256) void deg_count(const int* __restrict__ s, const int* __restrict__ r,
                                                 float* deg_s, float* deg_r, int E) {
    int e = blockIdx.x * 256 + threadIdx.x;
    if (e < E) {
        atomicAdd(&deg_s[s[e]], 1.0f);
        atomicAdd(&deg_r[r[e]], 1.0f);
    }
}

// exclusive scan of (deg_r - 1) over N elements, single block of 1024 threads.
// Also zeroes the cursor array. row_start[N] = total edge count.
__global__ __launch_bounds__(1024) void scan50k(const float* __restrict__ deg_r,
                                                int* __restrict__ row_start,
                                                int* __restrict__ cursor, int N) {
    __shared__ int wsum[16];
    __shared__ int carry;
    int tid = threadIdx.x, lane = tid & 63, wid = tid >> 6;
    if (tid == 0) carry = 0;
    __syncthreads();
    for (int base = 0; base < N; base += 1024) {
        int i = base + tid;
        int vv = (i < N) ? ((int)deg_r[i] - 1) : 0;
        int x = vv;
        #pragma unroll
        for (int off = 1; off < 64; off <<= 1) {
            int y = __shfl_up(x, off);
            if (lane >= off) x += y;
        }
        if (lane == 63) wsum[wid] = x;
        __syncthreads();
        if (tid == 0) {
            int acc = carry;
            #pragma unroll
            for (int w = 0; w < 16; ++w) { int t = wsum[w]; wsum[w] = acc; acc += t; }
            carry = acc;
        }
        __syncthreads();
        if (i < N) {
            row_start[i] = wsum[wid] + (x - vv);
            cursor[i] = 0;
        }
        __syncthreads();
    }
    if (tid == 0) row_start[N] = carry;
}

__global__ __launch_bounds__(256) void deg_fin(float* deg_s, float* deg_r, int N) {
    int i = blockIdx.x * 256 + threadIdx.x;
    if (i < N) {
        deg_s[i] = 1.0f / sqrtf(fmaxf(deg_s[i], 1.0f));  // becomes inv_sqrt_deg_s
        deg_r[i] = 1.0f / sqrtf(fmaxf(deg_r[i], 1.0f));  // becomes inv_sqrt_deg_r
    }
}

__global__ __launch_bounds__(256) void csr_fill(const int* __restrict__ s, const int* __restrict__ r,
                                                const int* __restrict__ row_start, int* cursor,
                                                int* __restrict__ csr_src, int E) {
    int e = blockIdx.x * 256 + threadIdx.x;
    if (e < E) {
        int rr = r[e];
        int slot = atomicAdd(&cursor[rr], 1);
        csr_src[row_start[rr] + slot] = s[e];
    }
}

// ---------------- embed: h = x @ W_embed + b_embed ----------------
__global__ __launch_bounds__(256) void embed_kernel(const float* __restrict__ x,
                                                    const float* __restrict__ W,
                                                    const float* __restrict__ b,
                                                    float* __restrict__ h, int N) {
    int idx = blockIdx.x * 256 + threadIdx.x;
    if (idx >= N * LATENT) return;
    int n = idx >> 7, j = idx & 127;
    float sacc = b[j];
    #pragma unroll
    for (int k = 0; k < F_IN; ++k) sacc = fmaf(x[n * F_IN + k], W[k * LATENT + j], sacc);
    h[idx] = sacc;
}

// ---------------- fused 2-layer MLP + inv_sqrt_deg_s scale ----------------
// block = 256 threads, 16 nodes per block; thread (j = tid&127, half = tid>>7)
// computes output column j for 8 nodes.
__global__ __launch_bounds__(256) void mlp_kernel(const float* __restrict__ h,
                                                  const float* __restrict__ W0, const float* __restrict__ b0,
                                                  const float* __restrict__ W1, const float* __restrict__ b1,
                                                  const float* __restrict__ inv_s,
                                                  float* __restrict__ v) {
    __shared__ __align__(16) float hs[16 * 128];
    __shared__ __align__(16) float us[16 * 128];
    int tid = threadIdx.x;
    int base = blockIdx.x * 16;

    for (int i = tid; i < 16 * 128; i += 256) hs[i] = h[base * 128 + i];
    __syncthreads();

    int j = tid & 127;
    int r0 = (tid >> 7) * 8;
    float acc[8];

    // layer 1
    {
        float bb = b0[j];
        #pragma unroll
        for (int q = 0; q < 8; ++q) acc[q] = bb;
        for (int k = 0; k < 128; k += 4) {
            float w0 = W0[(k + 0) * 128 + j];
            float w1 = W0[(k + 1) * 128 + j];
            float w2 = W0[(k + 2) * 128 + j];
            float w3 = W0[(k + 3) * 128 + j];
            #pragma unroll
            for (int q = 0; q < 8; ++q) {
                float4 hv = *reinterpret_cast<const float4*>(&hs[(r0 + q) * 128 + k]);
                acc[q] = fmaf(hv.x, w0, acc[q]);
                acc[q] = fmaf(hv.y, w1, acc[q]);
                acc[q] = fmaf(hv.z, w2, acc[q]);
                acc[q] = fmaf(hv.w, w3, acc[q]);
            }
        }
        #pragma unroll
        for (int q = 0; q < 8; ++q) us[(r0 + q) * 128 + j] = tanhf(acc[q]);
    }
    __syncthreads();

    // layer 2 + scale
    {
        float bb = b1[j];
        #pragma unroll
        for (int q = 0; q < 8; ++q) acc[q] = bb;
        for (int k = 0; k < 128; k += 4) {
            float w0 = W1[(k + 0) * 128 + j];
            float w1 = W1[(k + 1) * 128 + j];
            float w2 = W1[(k + 2) * 128 + j];
            float w3 = W1[(k + 3) * 128 + j];
            #pragma unroll
            for (int q = 0; q < 8; ++q) {
                float4 hv = *reinterpret_cast<const float4*>(&us[(r0 + q) * 128 + k]);
                acc[q] = fmaf(hv.x, w0, acc[q]);
                acc[q] = fmaf(hv.y, w1, acc[q]);
                acc[q] = fmaf(hv.z, w2, acc[q]);
                acc[q] = fmaf(hv.w, w3, acc[q]);
            }
        }
        #pragma unroll
        for (int q = 0; q < 8; ++q) {
            int n = base + r0 + q;
            v[n * 128 + j] = tanhf(acc[q]) * inv_s[n];
        }
    }
}

// ---------------- fused gather-aggregate + inv_r + skip + LayerNorm ----------------
// one 64-lane wave per node, 2 dims per lane; block = 4 waves = 4 nodes
__global__ __launch_bounds__(256) void agg_ln_kernel(const float* __restrict__ v,
                                                     const int* __restrict__ row_start,
                                                     const int* __restrict__ csr_src,
                                                     const float* __restrict__ inv_r,
                                                     const float* __restrict__ ln_scale,
                                                     const float* __restrict__ ln_bias,
                                                     float* __restrict__ h) {
    int lane = threadIdx.x & 63;
    int wave = threadIdx.x >> 6;
    int n = blockIdx.x * 4 + wave;
    int c0 = lane * 2;

    float2 acc = *reinterpret_cast<const float2*>(&v[n * 128 + c0]);  // self edge
    int lo = row_start[n], hi = row_start[n + 1];
    for (int p = lo; p < hi; ++p) {
        int src = csr_src[p];
        float2 t = *reinterpret_cast<const float2*>(&v[src * 128 + c0]);
        acc.x += t.x; acc.y += t.y;
    }
    float ir = inv_r[n];
    float2 hr = *reinterpret_cast<const float2*>(&h[n * 128 + c0]);
    float vx = fmaf(acc.x, ir, hr.x);
    float vy = fmaf(acc.y, ir, hr.y);

    float sred = vx + vy;
    #pragma unroll
    for (int off = 32; off; off >>= 1) sred += __shfl_xor(sred, off);
    float mu = sred * (1.0f / 128.0f);
    float dx = vx - mu, dy = vy - mu;
    float q = dx * dx + dy * dy;
    #pragma unroll
    for (int off = 32; off; off >>= 1) q += __shfl_xor(q, off);
    float rs = 1.0f / sqrtf(q * (1.0f / 128.0f) + LN_EPS);

    float2 outv;
    outv.x = fmaf(dx * rs, ln_scale[c0],     ln_bias[c0]);
    outv.y = fmaf(dy * rs, ln_scale[c0 + 1], ln_bias[c0 + 1]);
    *reinterpret_cast<float2*>(&h[n * 128 + c0]) = outv;
}

// ---------------- graph boundaries: gstart[g] = lower_bound(gids, g), g in [0,128] ----------------
__global__ __launch_bounds__(256) void gbounds_kernel(const int* __restrict__ gids,
                                                      int* __restrict__ gstart, int N) {
    int t = threadIdx.x;
    if (t > N_GRAPH) return;
    int lo = 0, hi = N;
    while (lo < hi) { int m = (lo + hi) >> 1; if (gids[m] < t) lo = m + 1; else hi = m; }
    gstart[t] = lo;
}

// ---------------- zero pooled accumulator ----------------
__global__ __launch_bounds__(256) void pool_zero(float* __restrict__ pooled) {
    pooled[blockIdx.x * 256 + threadIdx.x] = 0.0f;
}

// ---------------- segment-mean pool, phase 1: 8 chunks per graph, atomic partial sums ----------------
__global__ __launch_bounds__(128) void pool_partial(const float* __restrict__ h,
                                                    const int* __restrict__ gstart,
                                                    float* __restrict__ pooled) {
    int g = blockIdx.x >> 3;
    int sidx = blockIdx.x & 7;
    int start = gstart[g], end = gstart[g + 1];
    int len = end - start;
    int c0 = start + (len * sidx) / 8;
    int c1 = start + (len * (sidx + 1)) / 8;
    if (c1 <= c0) return;
    int j = threadIdx.x;
    float sacc = 0.0f;
    for (int n = c0; n < c1; ++n) sacc += h[n * 128 + j];
    atomicAdd(&pooled[g * 128 + j], sacc);
}

// ---------------- decode: out = (pooled/count) @ W_dec + b_dec ----------------
__global__ __launch_bounds__(128) void decode_kernel(const float* __restrict__ pooled,
                                                     const int* __restrict__ gstart,
                                                     const float* __restrict__ W_dec,
                                                     const float* __restrict__ b_dec,
                                                     float* __restrict__ out) {
    __shared__ float pl[128];
    int g = blockIdx.x;
    int cnt = gstart[g + 1] - gstart[g];
    float inv = 1.0f / (float)max(cnt, 1);
    pl[threadIdx.x] = pooled[g * 128 + threadIdx.x] * inv;
    __syncthreads();
    if (threadIdx.x < OUT_G) {
        int o = threadIdx.x;
        float sacc = b_dec[o];
        for (int jj = 0; jj < 128; ++jj) sacc = fmaf(pl[jj], W_dec[jj * OUT_G + o], sacc);
        out[g * OUT_G + o] = sacc;
    }
}

extern "C" void kernel_launch(void* const* d_in, const int* in_sizes, int n_in,
                              void* d_out, int out_size, void* d_ws, size_t ws_size,
                              hipStream_t stream) {
    const float* x        = (const float*)d_in[0];
    const int*   senders  = (const int*)d_in[1];
    const int*   receivers= (const int*)d_in[2];
    const int*   gids     = (const int*)d_in[3];
    const float* W_embed  = (const float*)d_in[4];
    const float* b_embed  = (const float*)d_in[5];
    const float* W_mlp    = (const float*)d_in[6];
    const float* b_mlp    = (const float*)d_in[7];
    const float* ln_scale = (const float*)d_in[8];
    const float* ln_bias  = (const float*)d_in[9];
    const float* W_dec    = (const float*)d_in[10];
    const float* b_dec    = (const float*)d_in[11];
    float* out = (float*)d_out;

    const int N = N_NODES, E = N_EDGES;
    char* ws = (char*)d_ws;
    size_t off = 0;
    auto alloc = [&](size_t bytes) { size_t o = off; off = (off + bytes + 255) & ~(size_t)255; return o; };
    float* h        = (float*)(ws + alloc((size_t)N * 128 * 4));
    float* v        = (float*)(ws + alloc((size_t)N * 128 * 4));
    float* deg_s    = (float*)(ws + alloc((size_t)N * 4));      // becomes inv_sqrt_deg_s
    float* deg_r    = (float*)(ws + alloc((size_t)N * 4));      // becomes inv_sqrt_deg_r
    int*   row_start= (int*)  (ws + alloc((size_t)(N + 1) * 4));
    int*   cursor   = (int*)  (ws + alloc((size_t)N * 4));
    int*   csr_src  = (int*)  (ws + alloc((size_t)E * 4));
    float* pooled   = (float*)(ws + alloc((size_t)N_GRAPH * 128 * 4));
    int*   gstart   = (int*)  (ws + alloc((size_t)(N_GRAPH + 1) * 4));

    deg_init <<<(N + 255) / 256, 256, 0, stream>>>(deg_s, deg_r, N);
    deg_count<<<(E + 255) / 256, 256, 0, stream>>>(senders, receivers, deg_s, deg_r, E);
    scan50k  <<<1, 1024, 0, stream>>>(deg_r, row_start, cursor, N);     // reads raw deg_r
    deg_fin  <<<(N + 255) / 256, 256, 0, stream>>>(deg_s, deg_r, N);    // in-place -> inv
    csr_fill <<<(E + 255) / 256, 256, 0, stream>>>(senders, receivers, row_start, cursor, csr_src, E);
    gbounds_kernel<<<1, 256, 0, stream>>>(gids, gstart, N);
    pool_zero<<<(N_GRAPH * 128) / 256, 256, 0, stream>>>(pooled);

    embed_kernel<<<(N * 128) / 256, 256, 0, stream>>>(x, W_embed, b_embed, h, N);

    for (int t = 0; t < STEPS; ++t) {
        const float* W0 = W_mlp + (size_t)(t * 2 + 0) * 128 * 128;
        const float* b0 = b_mlp + (size_t)(t * 2 + 0) * 128;
        const float* W1 = W_mlp + (size_t)(t * 2 + 1) * 128 * 128;
        const float* b1 = b_mlp + (size_t)(t * 2 + 1) * 128;
        mlp_kernel  <<<N / 16, 256, 0, stream>>>(h, W0, b0, W1, b1, deg_s, v);
        agg_ln_kernel<<<N / 4, 256, 0, stream>>>(v, row_start, csr_src, deg_r,
                                                 ln_scale + t * 128, ln_bias + t * 128, h);
    }

    pool_partial <<<N_GRAPH * 8, 128, 0, stream>>>(h, gstart, pooled);
    decode_kernel<<<N_GRAPH, 128, 0, stream>>>(pooled, gstart, W_dec, b_dec, out);
}

// Round 3
// 548.972 us; speedup vs baseline: 1.3967x; 1.2495x over previous
//
#include <hip/hip_runtime.h>
#include <hip/hip_bf16.h>

// Problem constants (from reference)
#define N_NODES 50000
#define N_EDGES 500000
#define N_GRAPH 128
#define F_IN    16
#define LATENT  128
#define STEPS   3
#define LN_EPS  1e-6f
#define OUT_G   10

typedef __attribute__((ext_vector_type(8))) short bf16x8;
typedef __attribute__((ext_vector_type(4))) float f32x4;

__device__ __forceinline__ ushort bf16_rtne(float x) {
    uint u = __float_as_uint(x);
    return (ushort)((u + 0x7FFFu + ((u >> 16) & 1u)) >> 16);
}
__device__ __forceinline__ float bf16_tof(ushort h) {
    return __uint_as_float(((uint)h) << 16);
}

// ---------------- degree kernels ----------------
__global__ __launch_bounds__(256) void deg_init(float* deg_s, float* deg_r, int N) {
    int i = blockIdx.x * 256 + threadIdx.x;
    if (i < N) { deg_s[i] = 1.0f; deg_r[i] = 1.0f; }  // self edge
}

__global__ __launch_bounds__(256) void deg_count(const int* __restrict__ s, const int* __restrict__ r,
                                                 float* deg_s, float* deg_r, int E) {
    int e = blockIdx.x * 256 + threadIdx.x;
    if (e < E) {
        atomicAdd(&deg_s[s[e]], 1.0f);
        atomicAdd(&deg_r[r[e]], 1.0f);
    }
}

// exclusive scan of (deg_r - 1) over N elements, single block of 1024 threads.
__global__ __launch_bounds__(1024) void scan50k(const float* __restrict__ deg_r,
                                                int* __restrict__ row_start,
                                                int* __restrict__ cursor, int N) {
    __shared__ int wsum[16];
    __shared__ int carry;
    int tid = threadIdx.x, lane = tid & 63, wid = tid >> 6;
    if (tid == 0) carry = 0;
    __syncthreads();
    for (int base = 0; base < N; base += 1024) {
        int i = base + tid;
        int vv = (i < N) ? ((int)deg_r[i] - 1) : 0;
        int x = vv;
        #pragma unroll
        for (int off = 1; off < 64; off <<= 1) {
            int y = __shfl_up(x, off);
            if (lane >= off) x += y;
        }
        if (lane == 63) wsum[wid] = x;
        __syncthreads();
        if (tid == 0) {
            int acc = carry;
            #pragma unroll
            for (int w = 0; w < 16; ++w) { int t = wsum[w]; wsum[w] = acc; acc += t; }
            carry = acc;
        }
        __syncthreads();
        if (i < N) {
            row_start[i] = wsum[wid] + (x - vv);
            cursor[i] = 0;
        }
        __syncthreads();
    }
    if (tid == 0) row_start[N] = carry;
}

__global__ __launch_bounds__(256) void deg_fin(float* deg_s, float* deg_r, int N) {
    int i = blockIdx.x * 256 + threadIdx.x;
    if (i < N) {
        deg_s[i] = 1.0f / sqrtf(fmaxf(deg_s[i], 1.0f));
        deg_r[i] = 1.0f / sqrtf(fmaxf(deg_r[i], 1.0f));
    }
}

__global__ __launch_bounds__(256) void csr_fill(const int* __restrict__ s, const int* __restrict__ r,
                                                const int* __restrict__ row_start, int* cursor,
                                                int* __restrict__ csr_src, int E) {
    int e = blockIdx.x * 256 + threadIdx.x;
    if (e < E) {
        int rr = r[e];
        int slot = atomicAdd(&cursor[rr], 1);
        csr_src[row_start[rr] + slot] = s[e];
    }
}

// ---------------- embed: h = x @ W_embed + b_embed ----------------
__global__ __launch_bounds__(256) void embed_kernel(const float* __restrict__ x,
                                                    const float* __restrict__ W,
                                                    const float* __restrict__ b,
                                                    float* __restrict__ h, int N) {
    int idx = blockIdx.x * 256 + threadIdx.x;
    if (idx >= N * LATENT) return;
    int n = idx >> 7, j = idx & 127;
    float sacc = b[j];
    #pragma unroll
    for (int k = 0; k < F_IN; ++k) sacc = fmaf(x[n * F_IN + k], W[k * LATENT + j], sacc);
    h[idx] = sacc;
}

// ---------------- weight prep: transpose + split to bf16 hi/lo ----------------
// W_mlp [6][128(k)][128(j)] f32 -> w_hi/w_lo [6][128(j)][128(k)] bf16
__global__ __launch_bounds__(256) void prep_w(const float* __restrict__ W,
                                              ushort* __restrict__ w_hi,
                                              ushort* __restrict__ w_lo) {
    int idx = blockIdx.x * 256 + threadIdx.x;        // 6*16384
    int tl = idx >> 14, rem = idx & 16383, j = rem >> 7, k = rem & 127;
    float x = W[(tl << 14) + k * 128 + j];
    ushort hi = bf16_rtne(x);
    ushort lo = bf16_rtne(x - bf16_tof(hi));
    w_hi[idx] = hi;
    w_lo[idx] = lo;
}

// ---------------- MFMA split-bf16 fused 2-layer MLP + inv_sqrt_deg_s scale ----------------
// 64 nodes/block, 4 waves; wave w owns output cols [w*32, w*32+32) for all 64 rows.
// A-frag: row=lane&15, k=(lane>>4)*8+j (8 contiguous bf16 from LDS row)
// B-frag: col=lane&15, k=(lane>>4)*8+j (8 contiguous bf16 from transposed weights)
// C/D   : col=lane&15, row=(lane>>4)*4+reg  [verified mapping]
__global__ __launch_bounds__(256) void mlp_mfma(const float* __restrict__ h,
                                                const ushort* __restrict__ wth,
                                                const ushort* __restrict__ wtl,
                                                const float* __restrict__ b0,
                                                const float* __restrict__ b1,
                                                const float* __restrict__ inv_s,
                                                float* __restrict__ v, int N) {
    __shared__ ushort sh_hi[64][136];
    __shared__ ushort sh_lo[64][136];
    const int tid = threadIdx.x;
    const int base = blockIdx.x * 64;

    // stage h tile -> split bf16 hi/lo in LDS
    #pragma unroll
    for (int it = 0; it < 8; ++it) {
        int e4 = tid + it * 256;           // 2048 float4 = 64 rows x 32
        int row = e4 >> 5, c4 = e4 & 31;
        int node = base + row;
        float4 hv = make_float4(0.f, 0.f, 0.f, 0.f);
        if (node < N) hv = *reinterpret_cast<const float4*>(&h[node * 128 + c4 * 4]);
        float xs[4] = {hv.x, hv.y, hv.z, hv.w};
        ushort hh[4], hl[4];
        #pragma unroll
        for (int q = 0; q < 4; ++q) {
            hh[q] = bf16_rtne(xs[q]);
            hl[q] = bf16_rtne(xs[q] - bf16_tof(hh[q]));
        }
        uint2 ph, pl;
        ph.x = (uint)hh[0] | ((uint)hh[1] << 16); ph.y = (uint)hh[2] | ((uint)hh[3] << 16);
        pl.x = (uint)hl[0] | ((uint)hl[1] << 16); pl.y = (uint)hl[2] | ((uint)hl[3] << 16);
        *reinterpret_cast<uint2*>(&sh_hi[row][c4 * 4]) = ph;
        *reinterpret_cast<uint2*>(&sh_lo[row][c4 * 4]) = pl;
    }
    __syncthreads();

    const int lane = tid & 63;
    const int wv = tid >> 6;
    const int lrow = lane & 15;
    const int lk = (lane >> 4) * 8;
    const int c0 = wv * 32;
    const int crow0 = (lane >> 4) * 4;

    f32x4 acc[4][2];

    // ---- layer 1 ----
    {
        float bb0 = b0[c0 + lrow], bb1 = b0[c0 + 16 + lrow];
        #pragma unroll
        for (int rt = 0; rt < 4; ++rt) {
            acc[rt][0] = (f32x4){bb0, bb0, bb0, bb0};
            acc[rt][1] = (f32x4){bb1, bb1, bb1, bb1};
        }
        #pragma unroll
        for (int kt = 0; kt < 4; ++kt) {
            int kk = kt * 32 + lk;
            bf16x8 bh0 = *reinterpret_cast<const bf16x8*>(&wth[(c0 + lrow) * 128 + kk]);
            bf16x8 bl0 = *reinterpret_cast<const bf16x8*>(&wtl[(c0 + lrow) * 128 + kk]);
            bf16x8 bh1 = *reinterpret_cast<const bf16x8*>(&wth[(c0 + 16 + lrow) * 128 + kk]);
            bf16x8 bl1 = *reinterpret_cast<const bf16x8*>(&wtl[(c0 + 16 + lrow) * 128 + kk]);
            #pragma unroll
            for (int rt = 0; rt < 4; ++rt) {
                bf16x8 ah = *reinterpret_cast<const bf16x8*>(&sh_hi[rt * 16 + lrow][kk]);
                bf16x8 al = *reinterpret_cast<const bf16x8*>(&sh_lo[rt * 16 + lrow][kk]);
                acc[rt][0] = __builtin_amdgcn_mfma_f32_16x16x32_bf16(ah, bh0, acc[rt][0], 0, 0, 0);
                acc[rt][0] = __builtin_amdgcn_mfma_f32_16x16x32_bf16(al, bh0, acc[rt][0], 0, 0, 0);
                acc[rt][0] = __builtin_amdgcn_mfma_f32_16x16x32_bf16(ah, bl0, acc[rt][0], 0, 0, 0);
                acc[rt][1] = __builtin_amdgcn_mfma_f32_16x16x32_bf16(ah, bh1, acc[rt][1], 0, 0, 0);
                acc[rt][1] = __builtin_amdgcn_mfma_f32_16x16x32_bf16(al, bh1, acc[rt][1], 0, 0, 0);
                acc[rt][1] = __builtin_amdgcn_mfma_f32_16x16x32_bf16(ah, bl1, acc[rt][1], 0, 0, 0);
            }
        }
    }
    __syncthreads();   // all waves done reading sh_* for layer 1

    // tanh + re-split into LDS (reuse buffers)
    #pragma unroll
    for (int rt = 0; rt < 4; ++rt) {
        #pragma unroll
        for (int ct = 0; ct < 2; ++ct) {
            int col = c0 + ct * 16 + lrow;
            #pragma unroll
            for (int r = 0; r < 4; ++r) {
                float uval = tanhf(acc[rt][ct][r]);
                int row = rt * 16 + crow0 + r;
                ushort uh = bf16_rtne(uval);
                ushort ul = bf16_rtne(uval - bf16_tof(uh));
                sh_hi[row][col] = uh;
                sh_lo[row][col] = ul;
            }
        }
    }
    __syncthreads();

    // ---- layer 2 ----
    {
        const ushort* w2h = wth + 128 * 128;
        const ushort* w2l = wtl + 128 * 128;
        float bb0 = b1[c0 + lrow], bb1 = b1[c0 + 16 + lrow];
        #pragma unroll
        for (int rt = 0; rt < 4; ++rt) {
            acc[rt][0] = (f32x4){bb0, bb0, bb0, bb0};
            acc[rt][1] = (f32x4){bb1, bb1, bb1, bb1};
        }
        #pragma unroll
        for (int kt = 0; kt < 4; ++kt) {
            int kk = kt * 32 + lk;
            bf16x8 bh0 = *reinterpret_cast<const bf16x8*>(&w2h[(c0 + lrow) * 128 + kk]);
            bf16x8 bl0 = *reinterpret_cast<const bf16x8*>(&w2l[(c0 + lrow) * 128 + kk]);
            bf16x8 bh1 = *reinterpret_cast<const bf16x8*>(&w2h[(c0 + 16 + lrow) * 128 + kk]);
            bf16x8 bl1 = *reinterpret_cast<const bf16x8*>(&w2l[(c0 + 16 + lrow) * 128 + kk]);
            #pragma unroll
            for (int rt = 0; rt < 4; ++rt) {
                bf16x8 ah = *reinterpret_cast<const bf16x8*>(&sh_hi[rt * 16 + lrow][kk]);
                bf16x8 al = *reinterpret_cast<const bf16x8*>(&sh_lo[rt * 16 + lrow][kk]);
                acc[rt][0] = __builtin_amdgcn_mfma_f32_16x16x32_bf16(ah, bh0, acc[rt][0], 0, 0, 0);
                acc[rt][0] = __builtin_amdgcn_mfma_f32_16x16x32_bf16(al, bh0, acc[rt][0], 0, 0, 0);
                acc[rt][0] = __builtin_amdgcn_mfma_f32_16x16x32_bf16(ah, bl0, acc[rt][0], 0, 0, 0);
                acc[rt][1] = __builtin_amdgcn_mfma_f32_16x16x32_bf16(ah, bh1, acc[rt][1], 0, 0, 0);
                acc[rt][1] = __builtin_amdgcn_mfma_f32_16x16x32_bf16(al, bh1, acc[rt][1], 0, 0, 0);
                acc[rt][1] = __builtin_amdgcn_mfma_f32_16x16x32_bf16(ah, bl1, acc[rt][1], 0, 0, 0);
            }
        }
    }

    // epilogue: tanh * inv_s -> v (f32)
    #pragma unroll
    for (int rt = 0; rt < 4; ++rt) {
        #pragma unroll
        for (int r = 0; r < 4; ++r) {
            int row = rt * 16 + crow0 + r;
            int node = base + row;
            if (node < N) {
                float is = inv_s[node];
                v[node * 128 + c0 + lrow]      = tanhf(acc[rt][0][r]) * is;
                v[node * 128 + c0 + 16 + lrow] = tanhf(acc[rt][1][r]) * is;
            }
        }
    }
}

// ---------------- fused gather-aggregate + inv_r + skip + LayerNorm ----------------
__global__ __launch_bounds__(256) void agg_ln_kernel(const float* __restrict__ v,
                                                     const int* __restrict__ row_start,
                                                     const int* __restrict__ csr_src,
                                                     const float* __restrict__ inv_r,
                                                     const float* __restrict__ ln_scale,
                                                     const float* __restrict__ ln_bias,
                                                     float* __restrict__ h) {
    int lane = threadIdx.x & 63;
    int wave = threadIdx.x >> 6;
    int n = blockIdx.x * 4 + wave;
    int c0 = lane * 2;

    float2 acc = *reinterpret_cast<const float2*>(&v[n * 128 + c0]);  // self edge
    int lo = row_start[n], hi = row_start[n + 1];
    for (int p = lo; p < hi; ++p) {
        int src = csr_src[p];
        float2 t = *reinterpret_cast<const float2*>(&v[src * 128 + c0]);
        acc.x += t.x; acc.y += t.y;
    }
    float ir = inv_r[n];
    float2 hr = *reinterpret_cast<const float2*>(&h[n * 128 + c0]);
    float vx = fmaf(acc.x, ir, hr.x);
    float vy = fmaf(acc.y, ir, hr.y);

    float sred = vx + vy;
    #pragma unroll
    for (int off = 32; off; off >>= 1) sred += __shfl_xor(sred, off);
    float mu = sred * (1.0f / 128.0f);
    float dx = vx - mu, dy = vy - mu;
    float q = dx * dx + dy * dy;
    #pragma unroll
    for (int off = 32; off; off >>= 1) q += __shfl_xor(q, off);
    float rs = 1.0f / sqrtf(q * (1.0f / 128.0f) + LN_EPS);

    float2 outv;
    outv.x = fmaf(dx * rs, ln_scale[c0],     ln_bias[c0]);
    outv.y = fmaf(dy * rs, ln_scale[c0 + 1], ln_bias[c0 + 1]);
    *reinterpret_cast<float2*>(&h[n * 128 + c0]) = outv;
}

// ---------------- graph boundaries ----------------
__global__ __launch_bounds__(256) void gbounds_kernel(const int* __restrict__ gids,
                                                      int* __restrict__ gstart, int N) {
    int t = threadIdx.x;
    if (t > N_GRAPH) return;
    int lo = 0, hi = N;
    while (lo < hi) { int m = (lo + hi) >> 1; if (gids[m] < t) lo = m + 1; else hi = m; }
    gstart[t] = lo;
}

__global__ __launch_bounds__(256) void pool_zero(float* __restrict__ pooled) {
    pooled[blockIdx.x * 256 + threadIdx.x] = 0.0f;
}

__global__ __launch_bounds__(128) void pool_partial(const float* __restrict__ h,
                                                    const int* __restrict__ gstart,
                                                    float* __restrict__ pooled) {
    int g = blockIdx.x >> 3;
    int sidx = blockIdx.x & 7;
    int start = gstart[g], end = gstart[g + 1];
    int len = end - start;
    int c0 = start + (len * sidx) / 8;
    int c1 = start + (len * (sidx + 1)) / 8;
    if (c1 <= c0) return;
    int j = threadIdx.x;
    float sacc = 0.0f;
    for (int n = c0; n < c1; ++n) sacc += h[n * 128 + j];
    atomicAdd(&pooled[g * 128 + j], sacc);
}

__global__ __launch_bounds__(128) void decode_kernel(const float* __restrict__ pooled,
                                                     const int* __restrict__ gstart,
                                                     const float* __restrict__ W_dec,
                                                     const float* __restrict__ b_dec,
                                                     float* __restrict__ out) {
    __shared__ float pl[128];
    int g = blockIdx.x;
    int cnt = gstart[g + 1] - gstart[g];
    float inv = 1.0f / (float)max(cnt, 1);
    pl[threadIdx.x] = pooled[g * 128 + threadIdx.x] * inv;
    __syncthreads();
    if (threadIdx.x < OUT_G) {
        int o = threadIdx.x;
        float sacc = b_dec[o];
        for (int jj = 0; jj < 128; ++jj) sacc = fmaf(pl[jj], W_dec[jj * OUT_G + o], sacc);
        out[g * OUT_G + o] = sacc;
    }
}

extern "C" void kernel_launch(void* const* d_in, const int* in_sizes, int n_in,
                              void* d_out, int out_size, void* d_ws, size_t ws_size,
                              hipStream_t stream) {
    const float* x        = (const float*)d_in[0];
    const int*   senders  = (const int*)d_in[1];
    const int*   receivers= (const int*)d_in[2];
    const int*   gids     = (const int*)d_in[3];
    const float* W_embed  = (const float*)d_in[4];
    const float* b_embed  = (const float*)d_in[5];
    const float* W_mlp    = (const float*)d_in[6];
    const float* b_mlp    = (const float*)d_in[7];
    const float* ln_scale = (const float*)d_in[8];
    const float* ln_bias  = (const float*)d_in[9];
    const float* W_dec    = (const float*)d_in[10];
    const float* b_dec    = (const float*)d_in[11];
    float* out = (float*)d_out;

    const int N = N_NODES, E = N_EDGES;
    char* ws = (char*)d_ws;
    size_t off = 0;
    auto alloc = [&](size_t bytes) { size_t o = off; off = (off + bytes + 255) & ~(size_t)255; return o; };
    float* h        = (float*)(ws + alloc((size_t)N * 128 * 4));
    float* v        = (float*)(ws + alloc((size_t)N * 128 * 4));
    float* deg_s    = (float*)(ws + alloc((size_t)N * 4));
    float* deg_r    = (float*)(ws + alloc((size_t)N * 4));
    int*   row_start= (int*)  (ws + alloc((size_t)(N + 1) * 4));
    int*   cursor   = (int*)  (ws + alloc((size_t)N * 4));
    int*   csr_src  = (int*)  (ws + alloc((size_t)E * 4));
    float* pooled   = (float*)(ws + alloc((size_t)N_GRAPH * 128 * 4));
    int*   gstart   = (int*)  (ws + alloc((size_t)(N_GRAPH + 1) * 4));
    ushort* w_hi    = (ushort*)(ws + alloc((size_t)STEPS * 2 * 128 * 128 * 2));
    ushort* w_lo    = (ushort*)(ws + alloc((size_t)STEPS * 2 * 128 * 128 * 2));

    deg_init <<<(N + 255) / 256, 256, 0, stream>>>(deg_s, deg_r, N);
    deg_count<<<(E + 255) / 256, 256, 0, stream>>>(senders, receivers, deg_s, deg_r, E);
    scan50k  <<<1, 1024, 0, stream>>>(deg_r, row_start, cursor, N);
    deg_fin  <<<(N + 255) / 256, 256, 0, stream>>>(deg_s, deg_r, N);
    csr_fill <<<(E + 255) / 256, 256, 0, stream>>>(senders, receivers, row_start, cursor, csr_src, E);
    gbounds_kernel<<<1, 256, 0, stream>>>(gids, gstart, N);
    pool_zero<<<(N_GRAPH * 128) / 256, 256, 0, stream>>>(pooled);
    prep_w   <<<(STEPS * 2 * 128 * 128) / 256, 256, 0, stream>>>(W_mlp, w_hi, w_lo);

    embed_kernel<<<(N * 128) / 256, 256, 0, stream>>>(x, W_embed, b_embed, h, N);

    for (int t = 0; t < STEPS; ++t) {
        const ushort* wth = w_hi + (size_t)t * 2 * 128 * 128;
        const ushort* wtl = w_lo + (size_t)t * 2 * 128 * 128;
        const float* bb0 = b_mlp + (size_t)(t * 2 + 0) * 128;
        const float* bb1 = b_mlp + (size_t)(t * 2 + 1) * 128;
        mlp_mfma<<<(N + 63) / 64, 256, 0, stream>>>(h, wth, wtl, bb0, bb1, deg_s, v, N);
        agg_ln_kernel<<<N / 4, 256, 0, stream>>>(v, row_start, csr_src, deg_r,
                                                 ln_scale + t * 128, ln_bias + t * 128, h);
    }

    pool_partial <<<N_GRAPH * 8, 128, 0, stream>>>(h, gstart, pooled);
    decode_kernel<<<N_GRAPH, 128, 0, stream>>>(pooled, gstart, W_dec, b_dec, out);
}

// Round 4
// 483.279 us; speedup vs baseline: 1.5866x; 1.1359x over previous
//
#include <hip/hip_runtime.h>
#include <hip/hip_bf16.h>

// Problem constants (from reference)
#define N_NODES 50000
#define N_EDGES 500000
#define N_GRAPH 128
#define F_IN    16
#define LATENT  128
#define STEPS   3
#define LN_EPS  1e-6f
#define OUT_G   10

typedef __attribute__((ext_vector_type(8))) short bf16x8;
typedef __attribute__((ext_vector_type(4))) float f32x4;

__device__ __forceinline__ ushort bf16_rtne(float x) {
    uint u = __float_as_uint(x);
    return (ushort)((u + 0x7FFFu + ((u >> 16) & 1u)) >> 16);
}
__device__ __forceinline__ float bf16_tof(ushort h) {
    return __uint_as_float(((uint)h) << 16);
}

// ---------------- degree kernels ----------------
__global__ __launch_bounds__(256) void deg_init(float* deg_s, float* deg_r, int N) {
    int i = blockIdx.x * 256 + threadIdx.x;
    if (i < N) { deg_s[i] = 1.0f; deg_r[i] = 1.0f; }  // self edge
}

__global__ __launch_bounds__(256) void deg_count(const int* __restrict__ s, const int* __restrict__ r,
                                                 float* deg_s, float* deg_r, int E) {
    int e = blockIdx.x * 256 + threadIdx.x;
    if (e < E) {
        atomicAdd(&deg_s[s[e]], 1.0f);
        atomicAdd(&deg_r[r[e]], 1.0f);
    }
}

// exclusive scan of (deg_r - 1) over N elements, single block of 1024 threads.
__global__ __launch_bounds__(1024) void scan50k(const float* __restrict__ deg_r,
                                                int* __restrict__ row_start,
                                                int* __restrict__ cursor, int N) {
    __shared__ int wsum[16];
    __shared__ int carry;
    int tid = threadIdx.x, lane = tid & 63, wid = tid >> 6;
    if (tid == 0) carry = 0;
    __syncthreads();
    for (int base = 0; base < N; base += 1024) {
        int i = base + tid;
        int vv = (i < N) ? ((int)deg_r[i] - 1) : 0;
        int x = vv;
        #pragma unroll
        for (int off = 1; off < 64; off <<= 1) {
            int y = __shfl_up(x, off);
            if (lane >= off) x += y;
        }
        if (lane == 63) wsum[wid] = x;
        __syncthreads();
        if (tid == 0) {
            int acc = carry;
            #pragma unroll
            for (int w = 0; w < 16; ++w) { int t = wsum[w]; wsum[w] = acc; acc += t; }
            carry = acc;
        }
        __syncthreads();
        if (i < N) {
            row_start[i] = wsum[wid] + (x - vv);
            cursor[i] = 0;
        }
        __syncthreads();
    }
    if (tid == 0) row_start[N] = carry;
}

__global__ __launch_bounds__(256) void deg_fin(float* deg_s, float* deg_r, int N) {
    int i = blockIdx.x * 256 + threadIdx.x;
    if (i < N) {
        deg_s[i] = 1.0f / sqrtf(fmaxf(deg_s[i], 1.0f));
        deg_r[i] = 1.0f / sqrtf(fmaxf(deg_r[i], 1.0f));
    }
}

__global__ __launch_bounds__(256) void csr_fill(const int* __restrict__ s, const int* __restrict__ r,
                                                const int* __restrict__ row_start, int* cursor,
                                                int* __restrict__ csr_src, int E) {
    int e = blockIdx.x * 256 + threadIdx.x;
    if (e < E) {
        int rr = r[e];
        int slot = atomicAdd(&cursor[rr], 1);
        csr_src[row_start[rr] + slot] = s[e];
    }
}

// ---------------- embed: h = x @ W_embed + b_embed ----------------
__global__ __launch_bounds__(256) void embed_kernel(const float* __restrict__ x,
                                                    const float* __restrict__ W,
                                                    const float* __restrict__ b,
                                                    float* __restrict__ h, int N) {
    int idx = blockIdx.x * 256 + threadIdx.x;
    if (idx >= N * LATENT) return;
    int n = idx >> 7, j = idx & 127;
    float sacc = b[j];
    #pragma unroll
    for (int k = 0; k < F_IN; ++k) sacc = fmaf(x[n * F_IN + k], W[k * LATENT + j], sacc);
    h[idx] = sacc;
}

// ---------------- weight prep: transpose + split to bf16 hi/lo ----------------
__global__ __launch_bounds__(256) void prep_w(const float* __restrict__ W,
                                              ushort* __restrict__ w_hi,
                                              ushort* __restrict__ w_lo) {
    int idx = blockIdx.x * 256 + threadIdx.x;        // 6*16384
    int tl = idx >> 14, rem = idx & 16383, j = rem >> 7, k = rem & 127;
    float x = W[(tl << 14) + k * 128 + j];
    ushort hi = bf16_rtne(x);
    ushort lo = bf16_rtne(x - bf16_tof(hi));
    w_hi[idx] = hi;
    w_lo[idx] = lo;
}

// ---------------- MFMA split-bf16 fused 2-layer MLP + inv_sqrt_deg_s scale ----------------
__global__ __launch_bounds__(256) void mlp_mfma(const float* __restrict__ h,
                                                const ushort* __restrict__ wth,
                                                const ushort* __restrict__ wtl,
                                                const float* __restrict__ b0,
                                                const float* __restrict__ b1,
                                                const float* __restrict__ inv_s,
                                                float* __restrict__ v, int N) {
    __shared__ ushort sh_hi[64][136];
    __shared__ ushort sh_lo[64][136];
    const int tid = threadIdx.x;
    const int base = blockIdx.x * 64;

    #pragma unroll
    for (int it = 0; it < 8; ++it) {
        int e4 = tid + it * 256;           // 2048 float4 = 64 rows x 32
        int row = e4 >> 5, c4 = e4 & 31;
        int node = base + row;
        float4 hv = make_float4(0.f, 0.f, 0.f, 0.f);
        if (node < N) hv = *reinterpret_cast<const float4*>(&h[node * 128 + c4 * 4]);
        float xs[4] = {hv.x, hv.y, hv.z, hv.w};
        ushort hh[4], hl[4];
        #pragma unroll
        for (int q = 0; q < 4; ++q) {
            hh[q] = bf16_rtne(xs[q]);
            hl[q] = bf16_rtne(xs[q] - bf16_tof(hh[q]));
        }
        uint2 ph, pl;
        ph.x = (uint)hh[0] | ((uint)hh[1] << 16); ph.y = (uint)hh[2] | ((uint)hh[3] << 16);
        pl.x = (uint)hl[0] | ((uint)hl[1] << 16); pl.y = (uint)hl[2] | ((uint)hl[3] << 16);
        *reinterpret_cast<uint2*>(&sh_hi[row][c4 * 4]) = ph;
        *reinterpret_cast<uint2*>(&sh_lo[row][c4 * 4]) = pl;
    }
    __syncthreads();

    const int lane = tid & 63;
    const int wv = tid >> 6;
    const int lrow = lane & 15;
    const int lk = (lane >> 4) * 8;
    const int c0 = wv * 32;
    const int crow0 = (lane >> 4) * 4;

    f32x4 acc[4][2];

    // ---- layer 1 ----
    {
        float bb0 = b0[c0 + lrow], bb1 = b0[c0 + 16 + lrow];
        #pragma unroll
        for (int rt = 0; rt < 4; ++rt) {
            acc[rt][0] = (f32x4){bb0, bb0, bb0, bb0};
            acc[rt][1] = (f32x4){bb1, bb1, bb1, bb1};
        }
        #pragma unroll
        for (int kt = 0; kt < 4; ++kt) {
            int kk = kt * 32 + lk;
            bf16x8 bh0 = *reinterpret_cast<const bf16x8*>(&wth[(c0 + lrow) * 128 + kk]);
            bf16x8 bl0 = *reinterpret_cast<const bf16x8*>(&wtl[(c0 + lrow) * 128 + kk]);
            bf16x8 bh1 = *reinterpret_cast<const bf16x8*>(&wth[(c0 + 16 + lrow) * 128 + kk]);
            bf16x8 bl1 = *reinterpret_cast<const bf16x8*>(&wtl[(c0 + 16 + lrow) * 128 + kk]);
            #pragma unroll
            for (int rt = 0; rt < 4; ++rt) {
                bf16x8 ah = *reinterpret_cast<const bf16x8*>(&sh_hi[rt * 16 + lrow][kk]);
                bf16x8 al = *reinterpret_cast<const bf16x8*>(&sh_lo[rt * 16 + lrow][kk]);
                acc[rt][0] = __builtin_amdgcn_mfma_f32_16x16x32_bf16(ah, bh0, acc[rt][0], 0, 0, 0);
                acc[rt][0] = __builtin_amdgcn_mfma_f32_16x16x32_bf16(al, bh0, acc[rt][0], 0, 0, 0);
                acc[rt][0] = __builtin_amdgcn_mfma_f32_16x16x32_bf16(ah, bl0, acc[rt][0], 0, 0, 0);
                acc[rt][1] = __builtin_amdgcn_mfma_f32_16x16x32_bf16(ah, bh1, acc[rt][1], 0, 0, 0);
                acc[rt][1] = __builtin_amdgcn_mfma_f32_16x16x32_bf16(al, bh1, acc[rt][1], 0, 0, 0);
                acc[rt][1] = __builtin_amdgcn_mfma_f32_16x16x32_bf16(ah, bl1, acc[rt][1], 0, 0, 0);
            }
        }
    }
    __syncthreads();

    // tanh + re-split into LDS (reuse buffers)
    #pragma unroll
    for (int rt = 0; rt < 4; ++rt) {
        #pragma unroll
        for (int ct = 0; ct < 2; ++ct) {
            int col = c0 + ct * 16 + lrow;
            #pragma unroll
            for (int r = 0; r < 4; ++r) {
                float uval = tanhf(acc[rt][ct][r]);
                int row = rt * 16 + crow0 + r;
                ushort uh = bf16_rtne(uval);
                ushort ul = bf16_rtne(uval - bf16_tof(uh));
                sh_hi[row][col] = uh;
                sh_lo[row][col] = ul;
            }
        }
    }
    __syncthreads();

    // ---- layer 2 ----
    {
        const ushort* w2h = wth + 128 * 128;
        const ushort* w2l = wtl + 128 * 128;
        float bb0 = b1[c0 + lrow], bb1 = b1[c0 + 16 + lrow];
        #pragma unroll
        for (int rt = 0; rt < 4; ++rt) {
            acc[rt][0] = (f32x4){bb0, bb0, bb0, bb0};
            acc[rt][1] = (f32x4){bb1, bb1, bb1, bb1};
        }
        #pragma unroll
        for (int kt = 0; kt < 4; ++kt) {
            int kk = kt * 32 + lk;
            bf16x8 bh0 = *reinterpret_cast<const bf16x8*>(&w2h[(c0 + lrow) * 128 + kk]);
            bf16x8 bl0 = *reinterpret_cast<const bf16x8*>(&w2l[(c0 + lrow) * 128 + kk]);
            bf16x8 bh1 = *reinterpret_cast<const bf16x8*>(&w2h[(c0 + 16 + lrow) * 128 + kk]);
            bf16x8 bl1 = *reinterpret_cast<const bf16x8*>(&w2l[(c0 + 16 + lrow) * 128 + kk]);
            #pragma unroll
            for (int rt = 0; rt < 4; ++rt) {
                bf16x8 ah = *reinterpret_cast<const bf16x8*>(&sh_hi[rt * 16 + lrow][kk]);
                bf16x8 al = *reinterpret_cast<const bf16x8*>(&sh_lo[rt * 16 + lrow][kk]);
                acc[rt][0] = __builtin_amdgcn_mfma_f32_16x16x32_bf16(ah, bh0, acc[rt][0], 0, 0, 0);
                acc[rt][0] = __builtin_amdgcn_mfma_f32_16x16x32_bf16(al, bh0, acc[rt][0], 0, 0, 0);
                acc[rt][0] = __builtin_amdgcn_mfma_f32_16x16x32_bf16(ah, bl0, acc[rt][0], 0, 0, 0);
                acc[rt][1] = __builtin_amdgcn_mfma_f32_16x16x32_bf16(ah, bh1, acc[rt][1], 0, 0, 0);
                acc[rt][1] = __builtin_amdgcn_mfma_f32_16x16x32_bf16(al, bh1, acc[rt][1], 0, 0, 0);
                acc[rt][1] = __builtin_amdgcn_mfma_f32_16x16x32_bf16(ah, bl1, acc[rt][1], 0, 0, 0);
            }
        }
    }

    // epilogue: tanh * inv_s -> v (f32)
    #pragma unroll
    for (int rt = 0; rt < 4; ++rt) {
        #pragma unroll
        for (int r = 0; r < 4; ++r) {
            int row = rt * 16 + crow0 + r;
            int node = base + row;
            if (node < N) {
                float is = inv_s[node];
                v[node * 128 + c0 + lrow]      = tanhf(acc[rt][0][r]) * is;
                v[node * 128 + c0 + 16 + lrow] = tanhf(acc[rt][1][r]) * is;
            }
        }
    }
}

// ---------------- fused gather-aggregate + inv_r + skip + LayerNorm ----------------
// one 64-lane wave per node, 2 dims per lane; block = 4 waves = 4 nodes.
// Indices fetched 64-at-a-time coalesced; gathers issued 8-deep to break
// the dependent load chain (R3: agg was latency-bound at 19% VALUBusy).
__global__ __launch_bounds__(256) void agg_ln_kernel(const float* __restrict__ v,
                                                     const int* __restrict__ row_start,
                                                     const int* __restrict__ csr_src,
                                                     const float* __restrict__ inv_r,
                                                     const float* __restrict__ ln_scale,
                                                     const float* __restrict__ ln_bias,
                                                     float* __restrict__ h) {
    int lane = threadIdx.x & 63;
    int wave = threadIdx.x >> 6;
    int n = blockIdx.x * 4 + wave;
    int c0 = lane * 2;

    int lo = row_start[n], hi = row_start[n + 1];
    int deg = hi - lo;

    // hoisted loads (overlap with gather)
    float ir = inv_r[n];
    float2 hr = *reinterpret_cast<const float2*>(&h[n * 128 + c0]);
    float2 acc = *reinterpret_cast<const float2*>(&v[n * 128 + c0]);  // self edge

    for (int b = 0; b < deg; b += 64) {
        int rem = deg - b;
        int cnt = rem < 64 ? rem : 64;
        int my = 0;
        if (lane < cnt) my = csr_src[lo + b + lane];   // one coalesced index load
        int k = 0;
        for (; k + 8 <= cnt; k += 8) {
            int s0 = __shfl(my, k + 0), s1 = __shfl(my, k + 1);
            int s2 = __shfl(my, k + 2), s3 = __shfl(my, k + 3);
            int s4 = __shfl(my, k + 4), s5 = __shfl(my, k + 5);
            int s6 = __shfl(my, k + 6), s7 = __shfl(my, k + 7);
            float2 t0 = *reinterpret_cast<const float2*>(&v[s0 * 128 + c0]);
            float2 t1 = *reinterpret_cast<const float2*>(&v[s1 * 128 + c0]);
            float2 t2 = *reinterpret_cast<const float2*>(&v[s2 * 128 + c0]);
            float2 t3 = *reinterpret_cast<const float2*>(&v[s3 * 128 + c0]);
            float2 t4 = *reinterpret_cast<const float2*>(&v[s4 * 128 + c0]);
            float2 t5 = *reinterpret_cast<const float2*>(&v[s5 * 128 + c0]);
            float2 t6 = *reinterpret_cast<const float2*>(&v[s6 * 128 + c0]);
            float2 t7 = *reinterpret_cast<const float2*>(&v[s7 * 128 + c0]);
            acc.x += ((t0.x + t1.x) + (t2.x + t3.x)) + ((t4.x + t5.x) + (t6.x + t7.x));
            acc.y += ((t0.y + t1.y) + (t2.y + t3.y)) + ((t4.y + t5.y) + (t6.y + t7.y));
        }
        if (k + 4 <= cnt) {
            int s0 = __shfl(my, k + 0), s1 = __shfl(my, k + 1);
            int s2 = __shfl(my, k + 2), s3 = __shfl(my, k + 3);
            float2 t0 = *reinterpret_cast<const float2*>(&v[s0 * 128 + c0]);
            float2 t1 = *reinterpret_cast<const float2*>(&v[s1 * 128 + c0]);
            float2 t2 = *reinterpret_cast<const float2*>(&v[s2 * 128 + c0]);
            float2 t3 = *reinterpret_cast<const float2*>(&v[s3 * 128 + c0]);
            acc.x += (t0.x + t1.x) + (t2.x + t3.x);
            acc.y += (t0.y + t1.y) + (t2.y + t3.y);
            k += 4;
        }
        for (; k < cnt; ++k) {
            int s = __shfl(my, k);
            float2 t = *reinterpret_cast<const float2*>(&v[s * 128 + c0]);
            acc.x += t.x; acc.y += t.y;
        }
    }

    float vx = fmaf(acc.x, ir, hr.x);
    float vy = fmaf(acc.y, ir, hr.y);

    float sred = vx + vy;
    #pragma unroll
    for (int off = 32; off; off >>= 1) sred += __shfl_xor(sred, off);
    float mu = sred * (1.0f / 128.0f);
    float dx = vx - mu, dy = vy - mu;
    float q = dx * dx + dy * dy;
    #pragma unroll
    for (int off = 32; off; off >>= 1) q += __shfl_xor(q, off);
    float rs = 1.0f / sqrtf(q * (1.0f / 128.0f) + LN_EPS);

    float2 outv;
    outv.x = fmaf(dx * rs, ln_scale[c0],     ln_bias[c0]);
    outv.y = fmaf(dy * rs, ln_scale[c0 + 1], ln_bias[c0 + 1]);
    *reinterpret_cast<float2*>(&h[n * 128 + c0]) = outv;
}

// ---------------- graph boundaries ----------------
__global__ __launch_bounds__(256) void gbounds_kernel(const int* __restrict__ gids,
                                                      int* __restrict__ gstart, int N) {
    int t = threadIdx.x;
    if (t > N_GRAPH) return;
    int lo = 0, hi = N;
    while (lo < hi) { int m = (lo + hi) >> 1; if (gids[m] < t) lo = m + 1; else hi = m; }
    gstart[t] = lo;
}

__global__ __launch_bounds__(256) void pool_zero(float* __restrict__ pooled) {
    pooled[blockIdx.x * 256 + threadIdx.x] = 0.0f;
}

__global__ __launch_bounds__(128) void pool_partial(const float* __restrict__ h,
                                                    const int* __restrict__ gstart,
                                                    float* __restrict__ pooled) {
    int g = blockIdx.x >> 3;
    int sidx = blockIdx.x & 7;
    int start = gstart[g], end = gstart[g + 1];
    int len = end - start;
    int c0 = start + (len * sidx) / 8;
    int c1 = start + (len * (sidx + 1)) / 8;
    if (c1 <= c0) return;
    int j = threadIdx.x;
    float sacc = 0.0f;
    for (int n = c0; n < c1; ++n) sacc += h[n * 128 + j];
    atomicAdd(&pooled[g * 128 + j], sacc);
}

__global__ __launch_bounds__(128) void decode_kernel(const float* __restrict__ pooled,
                                                     const int* __restrict__ gstart,
                                                     const float* __restrict__ W_dec,
                                                     const float* __restrict__ b_dec,
                                                     float* __restrict__ out) {
    __shared__ float pl[128];
    int g = blockIdx.x;
    int cnt = gstart[g + 1] - gstart[g];
    float inv = 1.0f / (float)max(cnt, 1);
    pl[threadIdx.x] = pooled[g * 128 + threadIdx.x] * inv;
    __syncthreads();
    if (threadIdx.x < OUT_G) {
        int o = threadIdx.x;
        float sacc = b_dec[o];
        for (int jj = 0; jj < 128; ++jj) sacc = fmaf(pl[jj], W_dec[jj * OUT_G + o], sacc);
        out[g * OUT_G + o] = sacc;
    }
}

extern "C" void kernel_launch(void* const* d_in, const int* in_sizes, int n_in,
                              void* d_out, int out_size, void* d_ws, size_t ws_size,
                              hipStream_t stream) {
    const float* x        = (const float*)d_in[0];
    const int*   senders  = (const int*)d_in[1];
    const int*   receivers= (const int*)d_in[2];
    const int*   gids     = (const int*)d_in[3];
    const float* W_embed  = (const float*)d_in[4];
    const float* b_embed  = (const float*)d_in[5];
    const float* W_mlp    = (const float*)d_in[6];
    const float* b_mlp    = (const float*)d_in[7];
    const float* ln_scale = (const float*)d_in[8];
    const float* ln_bias  = (const float*)d_in[9];
    const float* W_dec    = (const float*)d_in[10];
    const float* b_dec    = (const float*)d_in[11];
    float* out = (float*)d_out;

    const int N = N_NODES, E = N_EDGES;
    char* ws = (char*)d_ws;
    size_t off = 0;
    auto alloc = [&](size_t bytes) { size_t o = off; off = (off + bytes + 255) & ~(size_t)255; return o; };
    float* h        = (float*)(ws + alloc((size_t)N * 128 * 4));
    float* v        = (float*)(ws + alloc((size_t)N * 128 * 4));
    float* deg_s    = (float*)(ws + alloc((size_t)N * 4));
    float* deg_r    = (float*)(ws + alloc((size_t)N * 4));
    int*   row_start= (int*)  (ws + alloc((size_t)(N + 1) * 4));
    int*   cursor   = (int*)  (ws + alloc((size_t)N * 4));
    int*   csr_src  = (int*)  (ws + alloc((size_t)E * 4));
    float* pooled   = (float*)(ws + alloc((size_t)N_GRAPH * 128 * 4));
    int*   gstart   = (int*)  (ws + alloc((size_t)(N_GRAPH + 1) * 4));
    ushort* w_hi    = (ushort*)(ws + alloc((size_t)STEPS * 2 * 128 * 128 * 2));
    ushort* w_lo    = (ushort*)(ws + alloc((size_t)STEPS * 2 * 128 * 128 * 2));

    deg_init <<<(N + 255) / 256, 256, 0, stream>>>(deg_s, deg_r, N);
    deg_count<<<(E + 255) / 256, 256, 0, stream>>>(senders, receivers, deg_s, deg_r, E);
    scan50k  <<<1, 1024, 0, stream>>>(deg_r, row_start, cursor, N);
    deg_fin  <<<(N + 255) / 256, 256, 0, stream>>>(deg_s, deg_r, N);
    csr_fill <<<(E + 255) / 256, 256, 0, stream>>>(senders, receivers, row_start, cursor, csr_src, E);
    gbounds_kernel<<<1, 256, 0, stream>>>(gids, gstart, N);
    pool_zero<<<(N_GRAPH * 128) / 256, 256, 0, stream>>>(pooled);
    prep_w   <<<(STEPS * 2 * 128 * 128) / 256, 256, 0, stream>>>(W_mlp, w_hi, w_lo);

    embed_kernel<<<(N * 128) / 256, 256, 0, stream>>>(x, W_embed, b_embed, h, N);

    for (int t = 0; t < STEPS; ++t) {
        const ushort* wth = w_hi + (size_t)t * 2 * 128 * 128;
        const ushort* wtl = w_lo + (size_t)t * 2 * 128 * 128;
        const float* bb0 = b_mlp + (size_t)(t * 2 + 0) * 128;
        const float* bb1 = b_mlp + (size_t)(t * 2 + 1) * 128;
        mlp_mfma<<<(N + 63) / 64, 256, 0, stream>>>(h, wth, wtl, bb0, bb1, deg_s, v, N);
        agg_ln_kernel<<<N / 4, 256, 0, stream>>>(v, row_start, csr_src, deg_r,
                                                 ln_scale + t * 128, ln_bias + t * 128, h);
    }

    pool_partial <<<N_GRAPH * 8, 128, 0, stream>>>(h, gstart, pooled);
    decode_kernel<<<N_GRAPH, 128, 0, stream>>>(pooled, gstart, W_dec, b_dec, out);
}